// Round 11
// baseline (218.006 us; speedup 1.0000x reference)
//
#include <hip/hip_runtime.h>
#include <math.h>

#define NN 50000
#define EE 800000
#define ETOT 850000   // EE + NN self loops
#define INF 128
#define DD 64
#define CAP 64        // per-node slots; P(deg>64) ~ e^-44 for 1+Poisson(16)
#define NB_NODE 1024
#define WPITCH 132    // 128 + 4 pad, 16B-aligned rows

// ---------- helpers ----------
__device__ __forceinline__ float wsum64(float v) {
#pragma unroll
    for (int m = 1; m < 64; m <<= 1) v += __shfl_xor(v, m, 64);
    return v;
}
__device__ __forceinline__ float rlf(float v, int k) {   // k compile-time
    return __int_as_float(__builtin_amdgcn_readlane(__float_as_int(v), k));
}

// Minkowski inner of wave-uniform row ox[n] (xnv: one dim per lane) with
// row ox[j], full row loaded by THIS lane (16 independent float4 loads).
__device__ __forceinline__ float mink_full(const float* __restrict__ ox,
                                           int j, float xnv) {
    const float4* ojp = (const float4*)(ox + (size_t)(unsigned)j * DD);
    float4 oj[16];
#pragma unroll
    for (int q = 0; q < 16; ++q) oj[q] = ojp[q];
    float p0 = 0.f, p1 = 0.f, p2 = 0.f, p3 = 0.f;
#pragma unroll
    for (int q = 0; q < 16; ++q) {
        p0 = fmaf(rlf(xnv, 4 * q + 0), oj[q].x, p0);
        p1 = fmaf(rlf(xnv, 4 * q + 1), oj[q].y, p1);
        p2 = fmaf(rlf(xnv, 4 * q + 2), oj[q].z, p2);
        p3 = fmaf(rlf(xnv, 4 * q + 3), oj[q].w, p3);
    }
    return (p0 + p1 + p2 + p3) - 2.f * rlf(xnv, 0) * oj[0].x;
}

// ---------- K1: node transform, 8-node register tile + LDS W ----------
__global__ __launch_bounds__(256) void k_node(
    const float* __restrict__ x, const float* __restrict__ W,
    const float* __restrict__ b, const float* __restrict__ att,
    float* __restrict__ ox, float* __restrict__ ai, float2* __restrict__ snd)
{
    __shared__ float Wl[63 * WPITCH];   // 33264 B, col-major padded

    // stage W: Wl[c*WPITCH + k] = W[k*63 + c]; idx = k*64 + c, full k range
    for (int idx = threadIdx.x; idx < INF * 64; idx += 256) {
        int k = idx >> 6;
        int c = idx & 63;
        if (c < 63) Wl[c * WPITCH + k] = W[k * 63 + c];
    }
    __syncthreads();

    const int lane = threadIdx.x & 63;
    const int wid  = threadIdx.x >> 6;
    const int gw   = blockIdx.x * 4 + wid;          // 4096 waves
    const int col  = (lane == 0) ? 0 : lane - 1;
    const float4* wrow = (const float4*)(Wl + col * WPITCH);   // 16B aligned
    const float bcol = b[col];
    const float atti = att[lane];
    const float attj = att[DD + lane];

    for (int g = gw; g < NN / 8; g += NB_NODE * 4) {   // NN/8 = 6250 exact
        const int n0 = g * 8;

        // x tile: lane holds both 64-halves of 8 rows (16 VGPR)
        float xr[16];
#pragma unroll
        for (int t = 0; t < 8; ++t) {
            xr[2 * t]     = x[(size_t)(n0 + t) * INF + lane];
            xr[2 * t + 1] = x[(size_t)(n0 + t) * INF + 64 + lane];
        }

        float acc[8] = {0.f, 0.f, 0.f, 0.f, 0.f, 0.f, 0.f, 0.f};
#pragma unroll
        for (int q = 0; q < 16; ++q) {              // k = 4q..4q+3 (first half)
            float4 wv = wrow[q];
#pragma unroll
            for (int t = 0; t < 8; ++t) {
                acc[t] = fmaf(rlf(xr[2 * t], 4 * q + 0), wv.x, acc[t]);
                acc[t] = fmaf(rlf(xr[2 * t], 4 * q + 1), wv.y, acc[t]);
                acc[t] = fmaf(rlf(xr[2 * t], 4 * q + 2), wv.z, acc[t]);
                acc[t] = fmaf(rlf(xr[2 * t], 4 * q + 3), wv.w, acc[t]);
            }
        }
#pragma unroll
        for (int q = 16; q < 32; ++q) {             // k = 64.. (second half)
            float4 wv = wrow[q];
#pragma unroll
            for (int t = 0; t < 8; ++t) {
                acc[t] = fmaf(rlf(xr[2 * t + 1], 4 * (q - 16) + 0), wv.x, acc[t]);
                acc[t] = fmaf(rlf(xr[2 * t + 1], 4 * (q - 16) + 1), wv.y, acc[t]);
                acc[t] = fmaf(rlf(xr[2 * t + 1], 4 * (q - 16) + 2), wv.z, acc[t]);
                acc[t] = fmaf(rlf(xr[2 * t + 1], 4 * (q - 16) + 3), wv.w, acc[t]);
            }
        }

        // per-node epilogue (hyperbolic maps + att scalars)
#pragma unroll
        for (int t = 0; t < 8; ++t) {
            const int n = n0 + t;
            float xs = (lane == 0) ? 0.f : (acc[t] + bcol);

            float ss  = wsum64(xs * xs);
            float tm  = sqrtf(ss + 1.0f);             // C = 1
            float nrm = sqrtf(ss + 1e-15f);
            float d0  = acoshf(fmaxf(tm, 1.0f + 1e-6f));
            float scl = d0 / nrm;

            ox[(size_t)n * DD + lane] = (lane == 0) ? tm : xs;
            float lxv = (lane == 0) ? 0.f : scl * xs;

            float aiv = wsum64(lxv * atti);
            float ajv = wsum64(lxv * attj);
            if (lane == 0) { ai[n] = aiv; snd[n] = make_float2(ajv, scl); }
        }
    }
}

// ---------- K2: edge bucket placement (LDS-free, full occupancy) ----------
__global__ __launch_bounds__(256) void k_place(
    const int* __restrict__ ei0, const int* __restrict__ ei1,
    int* __restrict__ cnt, int* __restrict__ colPad)
{
    int e = blockIdx.x * 256 + threadIdx.x;
    if (e >= ETOT) return;
    int i, j;
    if (e < EE) { i = ei0[e]; j = ei1[e]; }
    else        { i = e - EE; j = i; }
    int pos = atomicAdd(&cnt[i], 1);
    if (pos < CAP) colPad[(size_t)i * CAP + pos] = j;
}

// ---------- K3: fused edge phase + epilogue: one wave per node ----------
__global__ __launch_bounds__(256) void k_fused(
    const int* __restrict__ cnt, const int* __restrict__ colPad,
    const float* __restrict__ ox, const float* __restrict__ ai,
    const float2* __restrict__ snd, float* __restrict__ y)
{
    const int lane = threadIdx.x & 63;
    const int wid  = threadIdx.x >> 6;
    const int n = blockIdx.x * 4 + wid;
    if (n >= NN) return;

    const int base = n * CAP;
    int deg = cnt[n];
    if (deg > CAP) deg = CAP;   // never triggers (safety)
    const float aii = ai[n];
    const float xnv = ox[(size_t)n * DD + lane];

    // ---- lane-per-edge fast path ----
    const bool act = lane < deg;
    const int  ecl = min(lane, deg - 1);
    const int  jreg = colPad[base + ecl];
    const float2 sv = snd[jreg];               // (aj, scl) 8B gather

    float inner = mink_full(ox, jreg, xnv);
    float arg = fmaxf(-inner, 1.0f + 1e-6f);
    float dd0 = acoshf(arg);
    float sq  = dd0 * dd0;

    // softmax 1 without max-subtraction: sq <= ~45 -> exp safe in f32
    float e1 = act ? expf(sq) : 0.f;
    float s1 = wsum64(e1) + 1e-16f;
    float al = (aii + sv.x) * e1 / s1;
    al = (al >= 0.f) ? al : 0.2f * al;
    // softmax 2 without max-subtraction: |al| = O(1)
    float p2 = act ? expf(al) : 0.f;
    float s2 = wsum64(p2);
    float w2 = p2 / (s2 + 1e-16f) * sv.y;      // fold scl_j

    // ---- sweep C: coalesced broadcast re-gather, 8 in flight ----
    float acc = 0.f;
    int k = 0;
    for (; k + 8 <= deg; k += 8) {
        float w0 = __shfl(w2, k + 0, 64), w1 = __shfl(w2, k + 1, 64);
        float w2b = __shfl(w2, k + 2, 64), w3 = __shfl(w2, k + 3, 64);
        float w4 = __shfl(w2, k + 4, 64), w5 = __shfl(w2, k + 5, 64);
        float w6 = __shfl(w2, k + 6, 64), w7 = __shfl(w2, k + 7, 64);
        int j0 = __shfl(jreg, k + 0, 64), j1 = __shfl(jreg, k + 1, 64);
        int j2 = __shfl(jreg, k + 2, 64), j3 = __shfl(jreg, k + 3, 64);
        int j4 = __shfl(jreg, k + 4, 64), j5 = __shfl(jreg, k + 5, 64);
        int j6 = __shfl(jreg, k + 6, 64), j7 = __shfl(jreg, k + 7, 64);
        float v0 = ox[(size_t)j0 * DD + lane], v1 = ox[(size_t)j1 * DD + lane];
        float v2 = ox[(size_t)j2 * DD + lane], v3 = ox[(size_t)j3 * DD + lane];
        float v4 = ox[(size_t)j4 * DD + lane], v5 = ox[(size_t)j5 * DD + lane];
        float v6 = ox[(size_t)j6 * DD + lane], v7 = ox[(size_t)j7 * DD + lane];
        acc = fmaf(w0, v0, acc);  acc = fmaf(w1, v1, acc);
        acc = fmaf(w2b, v2, acc); acc = fmaf(w3, v3, acc);
        acc = fmaf(w4, v4, acc);  acc = fmaf(w5, v5, acc);
        acc = fmaf(w6, v6, acc);  acc = fmaf(w7, v7, acc);
    }
    for (; k < deg; ++k) {
        float w = __shfl(w2, k, 64);
        int   j = __shfl(jreg, k, 64);
        acc = fmaf(w, ox[(size_t)j * DD + lane], acc);
    }

    // ---- fused epilogue: relu + exp map ----
    float usp = (lane == 0) ? 0.f : fmaxf(acc, 0.f);
    float ss = wsum64(usp * usp);
    float un = sqrtf(ss + 1e-15f);
    float sc = sinhf(un) / un;
    float sp = sc * usp;
    float time = sqrtf(sc * sc * ss + 1.0f);
    y[(size_t)n * DD + lane] = (lane == 0) ? time : sp;
}

extern "C" void kernel_launch(void* const* d_in, const int* in_sizes, int n_in,
                              void* d_out, int out_size, void* d_ws, size_t ws_size,
                              hipStream_t stream) {
    const float* x   = (const float*)d_in[0];
    const float* W   = (const float*)d_in[1];
    const float* b   = (const float*)d_in[2];
    const float* att = (const float*)d_in[3];
    const int*   ei  = (const int*)d_in[4];
    const int* ei0 = ei;
    const int* ei1 = ei + EE;
    float* out = (float*)d_out;

    // workspace layout (~26.5 MB)
    float*  ws  = (float*)d_ws;
    float*  ox  = ws;                                 // N*64
    float*  ai  = ox + (size_t)NN * DD;               // N
    float2* snd = (float2*)(ai + NN);                 // N float2 (8B aligned)
    int*    cnt    = (int*)(snd + NN);                // N
    int*    colPad = cnt + NN;                        // N*CAP

    hipMemsetAsync(cnt, 0, sizeof(int) * NN, stream);

    // edge bucket placement (LDS-free, full occupancy)
    k_place<<<(ETOT + 255) / 256, 256, 0, stream>>>(ei0, ei1, cnt, colPad);

    // node transform (8-node register tile, W in LDS)
    k_node<<<NB_NODE, 256, 0, stream>>>(x, W, b, att, ox, ai, snd);

    // fused edge phase + epilogue
    k_fused<<<(NN + 3) / 4, 256, 0, stream>>>(cnt, colPad, ox, ai, snd, out);
}

// Round 12
// 173.313 us; speedup vs baseline: 1.2579x; 1.2579x over previous
//
#include <hip/hip_runtime.h>
#include <math.h>

#define NN 50000
#define EE 800000
#define ETOT 850000   // EE + NN self loops
#define INF 128
#define DD 64
#define CAP 64        // per-node slots; P(deg>64) ~ e^-44 for 1+Poisson(16)
#define NB_NODE 2560
#define NB_EDGE ((ETOT + 255) / 256)

// ---------- helpers ----------
__device__ __forceinline__ float wsum64(float v) {
#pragma unroll
    for (int m = 1; m < 64; m <<= 1) v += __shfl_xor(v, m, 64);
    return v;
}
__device__ __forceinline__ float rlf(float v, int k) {   // k compile-time
    return __int_as_float(__builtin_amdgcn_readlane(__float_as_int(v), k));
}

// Minkowski inner of wave-uniform row ox[n] (xnv: one dim per lane) with
// row ox[j], full row loaded by THIS lane (16 independent float4 loads).
__device__ __forceinline__ float mink_full(const float* __restrict__ ox,
                                           int j, float xnv) {
    const float4* ojp = (const float4*)(ox + (size_t)(unsigned)j * DD);
    float4 oj[16];
#pragma unroll
    for (int q = 0; q < 16; ++q) oj[q] = ojp[q];
    float p0 = 0.f, p1 = 0.f, p2 = 0.f, p3 = 0.f;
#pragma unroll
    for (int q = 0; q < 16; ++q) {
        p0 = fmaf(rlf(xnv, 4 * q + 0), oj[q].x, p0);
        p1 = fmaf(rlf(xnv, 4 * q + 1), oj[q].y, p1);
        p2 = fmaf(rlf(xnv, 4 * q + 2), oj[q].z, p2);
        p3 = fmaf(rlf(xnv, 4 * q + 3), oj[q].w, p3);
    }
    return (p0 + p1 + p2 + p3) - 2.f * rlf(xnv, 0) * oj[0].x;
}

// ---------- K1: fused node transform + edge bucket-place (R6 structure) ----
__global__ __launch_bounds__(256) void k_node_place(
    const float* __restrict__ x, const float* __restrict__ W,
    const float* __restrict__ b, const float* __restrict__ att,
    const int* __restrict__ ei0, const int* __restrict__ ei1,
    float* __restrict__ ox, float* __restrict__ ai, float2* __restrict__ snd,
    int* __restrict__ cnt, int* __restrict__ colPad)
{
    if (blockIdx.x >= NB_NODE) {
        // ---- edge path: one-pass bucket placement ----
        int e = (blockIdx.x - NB_NODE) * 256 + threadIdx.x;
        if (e < ETOT) {
            int i, j;
            if (e < EE) { i = ei0[e]; j = ei1[e]; }
            else        { i = e - EE; j = i; }
            int pos = atomicAdd(&cnt[i], 1);
            if (pos < CAP) colPad[(size_t)i * CAP + pos] = j;
        }
        return;
    }

    // ---- node path (R6-proven): W cols nominally in VGPRs; compiler may
    // sink to L1-hot reloads -- measured ~89us @ NB_NODE=1024, tail-bound ----
    const int lane = threadIdx.x & 63;
    const int wid  = threadIdx.x >> 6;
    const int wgid = blockIdx.x * 4 + wid;
    const int nw   = NB_NODE * 4;

    const int col = (lane == 0) ? 0 : lane - 1;
    float wreg[INF];
#pragma unroll
    for (int k = 0; k < INF; ++k) wreg[k] = W[k * (DD - 1) + col];
    const float bcol = b[col];
    const float atti = att[lane];
    const float attj = att[DD + lane];

    if (wgid * 1 >= NN) return;
    float nxv0 = x[(size_t)wgid * INF + lane];
    float nxv1 = x[(size_t)wgid * INF + 64 + lane];

    for (int n = wgid; n < NN; n += nw) {
        float xv0 = nxv0, xv1 = nxv1;
        int np = n + nw;
        if (np < NN) {
            nxv0 = x[(size_t)np * INF + lane];
            nxv1 = x[(size_t)np * INF + 64 + lane];
        }
        float acc0 = 0.f, acc1 = 0.f;
#pragma unroll
        for (int k = 0; k < 64; k += 2) {
            acc0 = fmaf(rlf(xv0, k),     wreg[k],     acc0);
            acc1 = fmaf(rlf(xv0, k + 1), wreg[k + 1], acc1);
        }
#pragma unroll
        for (int k = 0; k < 64; k += 2) {
            acc0 = fmaf(rlf(xv1, k),     wreg[64 + k],     acc0);
            acc1 = fmaf(rlf(xv1, k + 1), wreg[64 + k + 1], acc1);
        }
        float xs = (lane == 0) ? 0.f : (acc0 + acc1 + bcol);

        float ss  = wsum64(xs * xs);
        float t   = sqrtf(ss + 1.0f);             // C = 1
        float nrm = sqrtf(ss + 1e-15f);
        float d0  = acoshf(fmaxf(t, 1.0f + 1e-6f));
        float scl = d0 / nrm;

        ox[(size_t)n * DD + lane] = (lane == 0) ? t : xs;
        float lxv = (lane == 0) ? 0.f : scl * xs;

        float aiv = wsum64(lxv * atti);
        float ajv = wsum64(lxv * attj);
        if (lane == 0) { ai[n] = aiv; snd[n] = make_float2(ajv, scl); }
    }
}

// ---------- K2: fused edge phase + epilogue: one wave per node ----------
__global__ __launch_bounds__(256) void k_fused(
    const int* __restrict__ cnt, const int* __restrict__ colPad,
    const float* __restrict__ ox, const float* __restrict__ ai,
    const float2* __restrict__ snd, float* __restrict__ y)
{
    const int lane = threadIdx.x & 63;
    const int wid  = threadIdx.x >> 6;
    const int n = blockIdx.x * 4 + wid;
    if (n >= NN) return;

    const int base = n * CAP;
    int deg = cnt[n];
    if (deg > CAP) deg = CAP;   // never triggers (safety)
    const float aii = ai[n];
    const float xnv = ox[(size_t)n * DD + lane];

    // ---- lane-per-edge fast path ----
    const bool act = lane < deg;
    const int  ecl = min(lane, deg - 1);
    const int  jreg = colPad[base + ecl];
    const float2 sv = snd[jreg];               // (aj, scl) 8B gather

    float inner = mink_full(ox, jreg, xnv);
    float arg = fmaxf(-inner, 1.0f + 1e-6f);
    float dd0 = acoshf(arg);
    float sq  = dd0 * dd0;

    // softmax 1 without max-subtraction: sq <= ~45 -> exp safe in f32
    float e1 = act ? expf(sq) : 0.f;
    float s1 = wsum64(e1) + 1e-16f;
    float al = (aii + sv.x) * e1 / s1;
    al = (al >= 0.f) ? al : 0.2f * al;
    // softmax 2 without max-subtraction: |al| = O(1)
    float p2 = act ? expf(al) : 0.f;
    float s2 = wsum64(p2);
    float w2 = p2 / (s2 + 1e-16f) * sv.y;      // fold scl_j

    // ---- sweep C: coalesced broadcast re-gather, 8 in flight ----
    float acc = 0.f;
    int k = 0;
    for (; k + 8 <= deg; k += 8) {
        float w0 = __shfl(w2, k + 0, 64), w1 = __shfl(w2, k + 1, 64);
        float w2b = __shfl(w2, k + 2, 64), w3 = __shfl(w2, k + 3, 64);
        float w4 = __shfl(w2, k + 4, 64), w5 = __shfl(w2, k + 5, 64);
        float w6 = __shfl(w2, k + 6, 64), w7 = __shfl(w2, k + 7, 64);
        int j0 = __shfl(jreg, k + 0, 64), j1 = __shfl(jreg, k + 1, 64);
        int j2 = __shfl(jreg, k + 2, 64), j3 = __shfl(jreg, k + 3, 64);
        int j4 = __shfl(jreg, k + 4, 64), j5 = __shfl(jreg, k + 5, 64);
        int j6 = __shfl(jreg, k + 6, 64), j7 = __shfl(jreg, k + 7, 64);
        float v0 = ox[(size_t)j0 * DD + lane], v1 = ox[(size_t)j1 * DD + lane];
        float v2 = ox[(size_t)j2 * DD + lane], v3 = ox[(size_t)j3 * DD + lane];
        float v4 = ox[(size_t)j4 * DD + lane], v5 = ox[(size_t)j5 * DD + lane];
        float v6 = ox[(size_t)j6 * DD + lane], v7 = ox[(size_t)j7 * DD + lane];
        acc = fmaf(w0, v0, acc);  acc = fmaf(w1, v1, acc);
        acc = fmaf(w2b, v2, acc); acc = fmaf(w3, v3, acc);
        acc = fmaf(w4, v4, acc);  acc = fmaf(w5, v5, acc);
        acc = fmaf(w6, v6, acc);  acc = fmaf(w7, v7, acc);
    }
    for (; k < deg; ++k) {
        float w = __shfl(w2, k, 64);
        int   j = __shfl(jreg, k, 64);
        acc = fmaf(w, ox[(size_t)j * DD + lane], acc);
    }

    // ---- fused epilogue: relu + exp map ----
    float usp = (lane == 0) ? 0.f : fmaxf(acc, 0.f);
    float ss = wsum64(usp * usp);
    float un = sqrtf(ss + 1e-15f);
    float sc = sinhf(un) / un;
    float sp = sc * usp;
    float time = sqrtf(sc * sc * ss + 1.0f);
    y[(size_t)n * DD + lane] = (lane == 0) ? time : sp;
}

extern "C" void kernel_launch(void* const* d_in, const int* in_sizes, int n_in,
                              void* d_out, int out_size, void* d_ws, size_t ws_size,
                              hipStream_t stream) {
    const float* x   = (const float*)d_in[0];
    const float* W   = (const float*)d_in[1];
    const float* b   = (const float*)d_in[2];
    const float* att = (const float*)d_in[3];
    const int*   ei  = (const int*)d_in[4];
    const int* ei0 = ei;
    const int* ei1 = ei + EE;
    float* out = (float*)d_out;

    // workspace layout (~26.5 MB)
    float*  ws  = (float*)d_ws;
    float*  ox  = ws;                                 // N*64
    float*  ai  = ox + (size_t)NN * DD;               // N
    float2* snd = (float2*)(ai + NN);                 // N float2 (8B aligned)
    int*    cnt    = (int*)(snd + NN);                // N
    int*    colPad = cnt + NN;                        // N*CAP

    hipMemsetAsync(cnt, 0, sizeof(int) * NN, stream);

    // fused node transform + edge bucket placement (one grid, node blocks first)
    k_node_place<<<NB_NODE + NB_EDGE, 256, 0, stream>>>(
        x, W, b, att, ei0, ei1, ox, ai, snd, cnt, colPad);

    // fused edge phase + epilogue
    k_fused<<<(NN + 3) / 4, 256, 0, stream>>>(cnt, colPad, ox, ai, snd, out);
}

// Round 13
// 146.762 us; speedup vs baseline: 1.4854x; 1.1809x over previous
//
#include <hip/hip_runtime.h>
#include <math.h>

#define NN 50000
#define EE 800000
#define ETOT 850000   // EE + NN self loops
#define INF 128
#define DD 64
#define CAP 64        // per-node slots; P(deg>64) ~ e^-44 for 1+Poisson(16)
#define NB_NODEBLK ((NN + 255) / 256)          // 196
#define NB_EDGE ((ETOT + 255) / 256)           // 3321
#define KCH 16
#define XPITCH 265    // conflict-free for both staged writes and k-major reads

// ---------- helpers ----------
__device__ __forceinline__ float wsum64(float v) {
#pragma unroll
    for (int m = 1; m < 64; m <<= 1) v += __shfl_xor(v, m, 64);
    return v;
}
__device__ __forceinline__ float rlf(float v, int k) {   // k compile-time
    return __int_as_float(__builtin_amdgcn_readlane(__float_as_int(v), k));
}

// Minkowski inner of wave-uniform row ox[n] (xnv: one dim per lane) with
// row ox[j], full row loaded by THIS lane (16 independent float4 loads).
__device__ __forceinline__ float mink_full(const float* __restrict__ ox,
                                           int j, float xnv) {
    const float4* ojp = (const float4*)(ox + (size_t)(unsigned)j * DD);
    float4 oj[16];
#pragma unroll
    for (int q = 0; q < 16; ++q) oj[q] = ojp[q];
    float p0 = 0.f, p1 = 0.f, p2 = 0.f, p3 = 0.f;
#pragma unroll
    for (int q = 0; q < 16; ++q) {
        p0 = fmaf(rlf(xnv, 4 * q + 0), oj[q].x, p0);
        p1 = fmaf(rlf(xnv, 4 * q + 1), oj[q].y, p1);
        p2 = fmaf(rlf(xnv, 4 * q + 2), oj[q].z, p2);
        p3 = fmaf(rlf(xnv, 4 * q + 3), oj[q].w, p3);
    }
    return (p0 + p1 + p2 + p3) - 2.f * rlf(xnv, 0) * oj[0].x;
}

// ---------- K1: node transform (thread-per-node, LDS x-tile, s_load W)
//              + edge bucket placement (extra blocks) ----------
__global__ __launch_bounds__(256) void k_node_place(
    const float* __restrict__ x, const float* __restrict__ W,
    const float* __restrict__ b, const float* __restrict__ att,
    const int* __restrict__ ei0, const int* __restrict__ ei1,
    float* __restrict__ ox, float* __restrict__ ai, float2* __restrict__ snd,
    int* __restrict__ cnt, int* __restrict__ colPad)
{
    __shared__ float Xl[KCH * XPITCH];   // 16.96 KB

    if (blockIdx.x >= NB_NODEBLK) {
        // ---- edge path: one-pass bucket placement ----
        int e = (blockIdx.x - NB_NODEBLK) * 256 + threadIdx.x;
        if (e < ETOT) {
            int i, j;
            if (e < EE) { i = ei0[e]; j = ei1[e]; }
            else        { i = e - EE; j = i; }
            int pos = atomicAdd(&cnt[i], 1);
            if (pos < CAP) colPad[(size_t)i * CAP + pos] = j;
        }
        return;
    }

    // ---- node path: thread t owns node n; acc[63] in VGPRs ----
    const int tid = threadIdx.x;
    const int n   = blockIdx.x * 256 + tid;

    float acc[63];
#pragma unroll
    for (int c = 0; c < 63; ++c) acc[c] = 0.f;

    const int nnq = tid >> 2;       // staging: node-slot within round
    const int q   = tid & 3;        // staging: float4 quad (k offset 4q)

    for (int k0 = 0; k0 < INF; k0 += KCH) {
        __syncthreads();            // protect previous chunk's reads
        // stage x[*, k0..k0+15] for 256 nodes: 4 rounds x (64 nodes x 16 k)
#pragma unroll
        for (int r = 0; r < 4; ++r) {
            int nn = nnq + 64 * r;
            int gn = min(blockIdx.x * 256 + nn, NN - 1);
            float4 v = *(const float4*)(x + (size_t)gn * INF + k0 + 4 * q);
            Xl[(4 * q + 0) * XPITCH + nn] = v.x;
            Xl[(4 * q + 1) * XPITCH + nn] = v.y;
            Xl[(4 * q + 2) * XPITCH + nn] = v.z;
            Xl[(4 * q + 3) * XPITCH + nn] = v.w;
        }
        __syncthreads();
        // compute: xk per-lane from LDS, W wave-uniform (scalar loads)
#pragma unroll
        for (int k = 0; k < KCH; ++k) {
            float xk = Xl[k * XPITCH + tid];
            const float* wr = W + (size_t)(k0 + k) * 63;
#pragma unroll
            for (int c = 0; c < 63; ++c)
                acc[c] = fmaf(xk, wr[c], acc[c]);
        }
    }

    if (n >= NN) return;

    // ---- per-node epilogue, fully per-lane (no cross-lane ops) ----
    float xs[63];
    float ss = 0.f;
#pragma unroll
    for (int c = 0; c < 63; ++c) {
        xs[c] = acc[c] + b[c];
        ss = fmaf(xs[c], xs[c], ss);
    }
    float t   = sqrtf(ss + 1.0f);             // C = 1
    float nrm = sqrtf(ss + 1e-15f);
    float d0  = acoshf(fmaxf(t, 1.0f + 1e-6f));
    float scl = d0 / nrm;

    float aiv = 0.f, ajv = 0.f;
#pragma unroll
    for (int c = 0; c < 63; ++c) {
        float lxv = scl * xs[c];
        aiv = fmaf(lxv, att[1 + c], aiv);
        ajv = fmaf(lxv, att[DD + 1 + c], ajv);
    }
    ai[n] = aiv;
    snd[n] = make_float2(ajv, scl);

    // ox row: [t, xs[0..62]] as 16 float4 stores
    float4* orow = (float4*)(ox + (size_t)n * DD);
    orow[0] = make_float4(t, xs[0], xs[1], xs[2]);
#pragma unroll
    for (int g = 1; g < 16; ++g)
        orow[g] = make_float4(xs[4 * g - 1], xs[4 * g], xs[4 * g + 1], xs[4 * g + 2]);
}

// ---------- K2: fused edge phase + epilogue: one wave per node ----------
__global__ __launch_bounds__(256) void k_fused(
    const int* __restrict__ cnt, const int* __restrict__ colPad,
    const float* __restrict__ ox, const float* __restrict__ ai,
    const float2* __restrict__ snd, float* __restrict__ y)
{
    const int lane = threadIdx.x & 63;
    const int wid  = threadIdx.x >> 6;
    const int n = blockIdx.x * 4 + wid;
    if (n >= NN) return;

    const int base = n * CAP;
    int deg = cnt[n];
    if (deg > CAP) deg = CAP;   // never triggers (safety)
    const float aii = ai[n];
    const float xnv = ox[(size_t)n * DD + lane];

    // ---- lane-per-edge fast path ----
    const bool act = lane < deg;
    const int  ecl = min(lane, deg - 1);
    const int  jreg = colPad[base + ecl];
    const float2 sv = snd[jreg];               // (aj, scl) 8B gather

    float inner = mink_full(ox, jreg, xnv);
    float arg = fmaxf(-inner, 1.0f + 1e-6f);
    float dd0 = acoshf(arg);
    float sq  = dd0 * dd0;

    // softmax 1 without max-subtraction: sq <= ~45 -> exp safe in f32
    float e1 = act ? expf(sq) : 0.f;
    float s1 = wsum64(e1) + 1e-16f;
    float al = (aii + sv.x) * e1 / s1;
    al = (al >= 0.f) ? al : 0.2f * al;
    // softmax 2 without max-subtraction: |al| = O(1)
    float p2 = act ? expf(al) : 0.f;
    float s2 = wsum64(p2);
    float w2 = p2 / (s2 + 1e-16f) * sv.y;      // fold scl_j

    // ---- sweep C: coalesced broadcast re-gather, 8 in flight ----
    float acc = 0.f;
    int k = 0;
    for (; k + 8 <= deg; k += 8) {
        float w0 = __shfl(w2, k + 0, 64), w1 = __shfl(w2, k + 1, 64);
        float w2b = __shfl(w2, k + 2, 64), w3 = __shfl(w2, k + 3, 64);
        float w4 = __shfl(w2, k + 4, 64), w5 = __shfl(w2, k + 5, 64);
        float w6 = __shfl(w2, k + 6, 64), w7 = __shfl(w2, k + 7, 64);
        int j0 = __shfl(jreg, k + 0, 64), j1 = __shfl(jreg, k + 1, 64);
        int j2 = __shfl(jreg, k + 2, 64), j3 = __shfl(jreg, k + 3, 64);
        int j4 = __shfl(jreg, k + 4, 64), j5 = __shfl(jreg, k + 5, 64);
        int j6 = __shfl(jreg, k + 6, 64), j7 = __shfl(jreg, k + 7, 64);
        float v0 = ox[(size_t)j0 * DD + lane], v1 = ox[(size_t)j1 * DD + lane];
        float v2 = ox[(size_t)j2 * DD + lane], v3 = ox[(size_t)j3 * DD + lane];
        float v4 = ox[(size_t)j4 * DD + lane], v5 = ox[(size_t)j5 * DD + lane];
        float v6 = ox[(size_t)j6 * DD + lane], v7 = ox[(size_t)j7 * DD + lane];
        acc = fmaf(w0, v0, acc);  acc = fmaf(w1, v1, acc);
        acc = fmaf(w2b, v2, acc); acc = fmaf(w3, v3, acc);
        acc = fmaf(w4, v4, acc);  acc = fmaf(w5, v5, acc);
        acc = fmaf(w6, v6, acc);  acc = fmaf(w7, v7, acc);
    }
    for (; k < deg; ++k) {
        float w = __shfl(w2, k, 64);
        int   j = __shfl(jreg, k, 64);
        acc = fmaf(w, ox[(size_t)j * DD + lane], acc);
    }

    // ---- fused epilogue: relu + exp map ----
    float usp = (lane == 0) ? 0.f : fmaxf(acc, 0.f);
    float ss = wsum64(usp * usp);
    float un = sqrtf(ss + 1e-15f);
    float sc = sinhf(un) / un;
    float sp = sc * usp;
    float time = sqrtf(sc * sc * ss + 1.0f);
    y[(size_t)n * DD + lane] = (lane == 0) ? time : sp;
}

extern "C" void kernel_launch(void* const* d_in, const int* in_sizes, int n_in,
                              void* d_out, int out_size, void* d_ws, size_t ws_size,
                              hipStream_t stream) {
    const float* x   = (const float*)d_in[0];
    const float* W   = (const float*)d_in[1];
    const float* b   = (const float*)d_in[2];
    const float* att = (const float*)d_in[3];
    const int*   ei  = (const int*)d_in[4];
    const int* ei0 = ei;
    const int* ei1 = ei + EE;
    float* out = (float*)d_out;

    // workspace layout (~26.5 MB)
    float*  ws  = (float*)d_ws;
    float*  ox  = ws;                                 // N*64
    float*  ai  = ox + (size_t)NN * DD;               // N
    float2* snd = (float2*)(ai + NN);                 // N float2 (8B aligned)
    int*    cnt    = (int*)(snd + NN);                // N
    int*    colPad = cnt + NN;                        // N*CAP

    hipMemsetAsync(cnt, 0, sizeof(int) * NN, stream);

    // node transform + edge bucket placement (one grid, node blocks first)
    k_node_place<<<NB_NODEBLK + NB_EDGE, 256, 0, stream>>>(
        x, W, b, att, ei0, ei1, ox, ai, snd, cnt, colPad);

    // fused edge phase + epilogue
    k_fused<<<(NN + 3) / 4, 256, 0, stream>>>(cnt, colPad, ox, ai, snd, out);
}